// Round 16
// baseline (311.969 us; speedup 1.0000x reference)
//
#include <hip/hip_runtime.h>

// AdaTTSp on MI355X. B=32768, T=8, E=2, NE=16, D=H=128, L=2.
// Round 16 = r15 kernels with two layout/locality changes:
//  (a) eo e-major [e][row][col]: kexp's per-tile flush = one contiguous
//      16KB region (r11-r15 invariant: kexp dur == WRITE_SIZE/1.3TB/s —
//      the [row][e][col] 256B@4KB-stride pattern capped the write path;
//      fillBuffer does 6.9 TB/s on this chip)
//  (b) 4-chunk pipeline (8192 rows through both layers): eo chunk 32MB and
//      x1h chunk 16MB stay L2/L3-resident between kernels -> eo mostly
//      never reaches HBM; kmix reads at L3 latency.
// Kernel internals (weights, staging, swizzles, numerics) = r15 verbatim.

typedef float f32x4 __attribute__((ext_vector_type(4)));
typedef _Float16 f16;
typedef f16 f16x8 __attribute__((ext_vector_type(8)));
typedef f16 f16x4 __attribute__((ext_vector_type(4)));

#define MFMA(a, b, c) __builtin_amdgcn_mfma_f32_16x16x32_f16(a, b, c, 0, 0, 0)
#define LOSC (1.0f / 2048.0f)
#define CH 8192  // chunk rows

__device__ __forceinline__ void split2h(float f, f16& h, f16& l) {
  h = (f16)f;
  l = (f16)((f - (float)h) * 2048.0f);
}

// ---------------------------------------------------------------------------
// Weight transform. w1T/w2T: single-fp16 fragment arrays; gwT hi/lo pair.
__global__ __launch_bounds__(256) void kxform(
    const float* __restrict__ w1, const float* __restrict__ w2,
    const float* __restrict__ gw, f16* __restrict__ w1T,
    f16* __restrict__ w2T, f16* __restrict__ gwT) {
  int idx = blockIdx.x * 256 + threadIdx.x;
  if (idx < 131072) {
    const float* src = (idx < 65536) ? w1 : w2;
    f16* dst = (idx < 65536) ? w1T : w2T;
    int i = idx & 65535;
    int lane = i & 63;
    int it = (i >> 6) & 7;
    int ks = (i >> 9) & 3;
    int q = i >> 11;
    int g = lane >> 4, le = lane & 15;
    f16x8 vh;
#pragma unroll
    for (int j = 0; j < 8; ++j)
      vh[j] = (f16)src[((size_t)q * 128 + (32 * ks + 8 * g + j)) * 128 + 16 * it + le];
    *(f16x8*)(dst + (size_t)i * 8) = vh;
  } else {
    int i = idx - 131072;
    if (i >= 4096) return;
    int lane = i & 63;
    int ks = (i >> 6) & 3;
    int q = (i >> 8) & 15;
    int g = lane >> 4, le = lane & 15;
    f16x8 vh, vl;
#pragma unroll
    for (int j = 0; j < 8; ++j) {
      float f = gw[((size_t)q * 128 + (32 * ks + 8 * g + j)) * 16 + le];
      f16 h, l;
      split2h(f, h, l);
      vh[j] = h;
      vl[j] = l;
    }
    *(f16x8*)(gwT + (size_t)i * 8) = vh;
    *(f16x8*)(gwT + 32768 + (size_t)i * 8) = vl;
  }
}

// ---------------------------------------------------------------------------
// Expert kernel, one 8192-row chunk. grid = 32 rowblocks(256) x 16 experts
// = 512 blocks; 256 thr (4 waves), 2 blocks/CU. 4 tiles x 64 rows per block.
// Schedule/tile: stage_load(t+1) | flush eo(t-1) | GEMM1 | bar |
//                GEMM2 -> sEO | stage_write(t+1) | bar.
// eo layout: E-MAJOR [e][chunk-row][col] -> flush is fully contiguous 16KB.
__global__ __launch_bounds__(256, 2) void kexp(
    const float* __restrict__ x0, const f16* __restrict__ x1in,
    const f16* __restrict__ w1T, const f16* __restrict__ w2T,
    const float* __restrict__ b1, const float* __restrict__ b2,
    f16* __restrict__ eo, int layer, int c0) {
  __shared__ f16 sX[2][8192];  // 64 x 128, dbuf (32KB)
  __shared__ f16 sH[8192];     // 16KB
  __shared__ f16 sEO[8192];    // 16KB
  const int tid = threadIdx.x;
  const int lane = tid & 63;
  const int it2 = tid >> 6;
  const int g = lane >> 4, le = lane & 15;
  const int e = blockIdx.x & 15;
  const int r0l = (blockIdx.x >> 4) * 256;  // chunk-local row base
  const int te = e >> 1;
  const int lx = layer * 16 + e;

  // ---- resident single-fp16 weight fragments (it = 2*it2 + i2) ----
  f16x8 w1r[2][4], w2r[2][4];
#pragma unroll
  for (int i2 = 0; i2 < 2; ++i2)
#pragma unroll
    for (int ks = 0; ks < 4; ++ks) {
      size_t fb = ((size_t)((lx * 4 + ks) * 8 + 2 * it2 + i2) * 64 + lane) * 8;
      w1r[i2][ks] = *(const f16x8*)(w1T + fb);
      w2r[i2][ks] = *(const f16x8*)(w2T + fb);
    }
  f32x4 b1v[2], b2v[2];
#pragma unroll
  for (int i2 = 0; i2 < 2; ++i2) {
    b1v[i2] = *(const f32x4*)(b1 + lx * 128 + 32 * it2 + 16 * i2 + 4 * g);
    b2v[i2] = *(const f32x4*)(b2 + lx * 128 + 32 * it2 + 16 * i2 + 4 * g);
  }

  // ---- async staging: thread -> row = tid>>2, granules gr..gr+3 ----
  const int srow = tid >> 2;
  const int gr = (tid & 3) * 4;
  f16x8 pre[4];
  auto stage_load = [&](int tile) {
    size_t base =
        ((size_t)(c0 + r0l + tile * 64 + srow) * 8 + te) * 128 + gr * 8;
    if (layer == 0) {
#pragma unroll
      for (int q = 0; q < 4; ++q) {
        f32x4 f0 = *(const f32x4*)(x0 + base + q * 8);
        f32x4 f1 = *(const f32x4*)(x0 + base + q * 8 + 4);
#pragma unroll
        for (int z = 0; z < 4; ++z) {
          pre[q][z] = (f16)f0[z];
          pre[q][4 + z] = (f16)f1[z];
        }
      }
    } else {
#pragma unroll
      for (int q = 0; q < 4; ++q)
        pre[q] = *(const f16x8*)(x1in + base + q * 8);
    }
  };
  auto stage_write = [&](int buf) {
#pragma unroll
    for (int q = 0; q < 4; ++q)
      *(f16x8*)(&sX[buf][srow * 128 + 8 * ((gr + q) ^ (srow & 7))]) = pre[q];
  };
  // ---- contiguous e-major eo flush: block tile = one 16KB region ----
  auto eo_flush = [&](int tile) {
#pragma unroll
    for (int i = 0; i < 4; ++i) {
      int slot = i * 256 + tid;
      int row = slot >> 4, c = slot & 15;
      f16x8 v = *(const f16x8*)(&sEO[row * 128 + 8 * (c ^ (row & 7))]);
      *(f16x8*)(eo + ((size_t)e * CH + (r0l + tile * 64 + row)) * 128 + 8 * c) = v;
    }
  };

  stage_load(0);
  stage_write(0);
  __syncthreads();

  for (int tile = 0; tile < 4; ++tile) {
    const int b = tile & 1;
    if (tile < 3) stage_load(tile + 1);
    if (tile > 0) eo_flush(tile - 1);
    // ---- GEMM1: h = relu(w1^T x^T + b1) -> sH ----
    {
      f32x4 a[2][4];
#pragma unroll
      for (int i2 = 0; i2 < 2; ++i2)
#pragma unroll
        for (int j = 0; j < 4; ++j) a[i2][j] = f32x4{0.f, 0.f, 0.f, 0.f};
#pragma unroll
      for (int ks = 0; ks < 4; ++ks)
#pragma unroll
        for (int j = 0; j < 4; ++j) {
          int brow = 16 * j + le;
          f16x8 bf = *(const f16x8*)(&sX[b][brow * 128 + 8 * ((4 * ks + g) ^ (brow & 7))]);
#pragma unroll
          for (int i2 = 0; i2 < 2; ++i2)
            a[i2][j] = MFMA(w1r[i2][ks], bf, a[i2][j]);
        }
#pragma unroll
      for (int i2 = 0; i2 < 2; ++i2)
#pragma unroll
        for (int j = 0; j < 4; ++j) {
          int brow = 16 * j + le;
          f16x4 hv;
#pragma unroll
          for (int r = 0; r < 4; ++r)
            hv[r] = (f16)fmaxf(a[i2][j][r] + b1v[i2][r], 0.f);
          *(f16x4*)(&sH[brow * 128 + 8 * ((4 * it2 + 2 * i2 + (g >> 1)) ^ (brow & 7)) +
                        4 * (g & 1)]) = hv;
        }
    }
    __syncthreads();
    // ---- GEMM2: eo = relu(w2^T h^T + b2) -> sEO ----
    {
      f32x4 a[2][4];
#pragma unroll
      for (int i2 = 0; i2 < 2; ++i2)
#pragma unroll
        for (int j = 0; j < 4; ++j) a[i2][j] = f32x4{0.f, 0.f, 0.f, 0.f};
#pragma unroll
      for (int ks = 0; ks < 4; ++ks)
#pragma unroll
        for (int j = 0; j < 4; ++j) {
          int brow = 16 * j + le;
          f16x8 bf = *(const f16x8*)(&sH[brow * 128 + 8 * ((4 * ks + g) ^ (brow & 7))]);
#pragma unroll
          for (int i2 = 0; i2 < 2; ++i2)
            a[i2][j] = MFMA(w2r[i2][ks], bf, a[i2][j]);
        }
#pragma unroll
      for (int i2 = 0; i2 < 2; ++i2)
#pragma unroll
        for (int j = 0; j < 4; ++j) {
          int brow = 16 * j + le;
          f16x4 ev;
#pragma unroll
          for (int r = 0; r < 4; ++r)
            ev[r] = (f16)fmaxf(a[i2][j][r] + b2v[i2][r], 0.f);
          *(f16x4*)(&sEO[brow * 128 + 8 * ((4 * it2 + 2 * i2 + (g >> 1)) ^ (brow & 7)) +
                         4 * (g & 1)]) = ev;
        }
    }
    if (tile < 3) stage_write(b ^ 1);
#pragma unroll
    for (int i2 = 0; i2 < 2; ++i2)
#pragma unroll
      for (int ks = 0; ks < 4; ++ks) {
        asm volatile("" : "+v"(w1r[i2][ks]));
        asm volatile("" : "+v"(w2r[i2][ks]));
      }
    __syncthreads();
  }
  eo_flush(3);
}

// ---------------------------------------------------------------------------
// Gate + mix kernel, one 8192-row chunk. grid = 256 blocks (32 rows), 512 thr.
__global__ __launch_bounds__(512, 4) void kmix(
    const float* __restrict__ x0, const f16* __restrict__ x1in,
    const f16* __restrict__ gwT, const float* __restrict__ gb,
    const float* __restrict__ sw, const f16* __restrict__ eo,
    f16* __restrict__ x1out, float* __restrict__ fout, int layer, int c0) {
  __shared__ float sG[8 * 16 * 32];  // [t][e][row32] 16KB
  const int tid = threadIdx.x;
  const int lane = tid & 63;
  const int t = tid >> 6;
  const int g = lane >> 4, le = lane & 15;
  const int lr0 = blockIdx.x * 32;  // chunk-local row base
  const int lt = layer * 8 + t;

  {  // ---- gates ----
    f32x4 l1[2], l2[2];
#pragma unroll
    for (int j = 0; j < 2; ++j) {
      l1[j] = f32x4{0.f, 0.f, 0.f, 0.f};
      l2[j] = f32x4{0.f, 0.f, 0.f, 0.f};
    }
#pragma unroll
    for (int ks = 0; ks < 4; ++ks) {
      size_t fb = ((size_t)(lt * 4 + ks) * 64 + lane) * 8;
      f16x8 ah = *(const f16x8*)(gwT + fb);
      f16x8 al = *(const f16x8*)(gwT + 32768 + fb);
#pragma unroll
      for (int j = 0; j < 2; ++j) {
        size_t xoff =
            ((size_t)(c0 + lr0 + 16 * j + le) * 8 + t) * 128 + 32 * ks + 8 * g;
        f16x8 bf;
        if (layer == 0) {
          f32x4 f0 = *(const f32x4*)(x0 + xoff);
          f32x4 f1 = *(const f32x4*)(x0 + xoff + 4);
#pragma unroll
          for (int z = 0; z < 4; ++z) {
            bf[z] = (f16)f0[z];
            bf[4 + z] = (f16)f1[z];
          }
        } else {
          bf = *(const f16x8*)(x1in + xoff);
        }
        l1[j] = MFMA(ah, bf, l1[j]);
        l2[j] = MFMA(al, bf, l2[j]);
      }
    }
#pragma unroll
    for (int j = 0; j < 2; ++j) {
      float zb[4];
#pragma unroll
      for (int r = 0; r < 4; ++r)
        zb[r] = l1[j][r] + l2[j][r] * LOSC + gb[lt * 16 + 4 * g + r];
      float m4 = fmaxf(fmaxf(zb[0], zb[1]), fmaxf(zb[2], zb[3]));
      m4 = fmaxf(m4, __shfl_xor(m4, 16, 64));
      m4 = fmaxf(m4, __shfl_xor(m4, 32, 64));
      float p4[4], s4 = 0.f;
#pragma unroll
      for (int r = 0; r < 4; ++r) {
        p4[r] = __expf(zb[r] - m4);
        s4 += p4[r];
      }
      s4 += __shfl_xor(s4, 16, 64);
      s4 += __shfl_xor(s4, 32, 64);
      float inv = 1.f / s4;
#pragma unroll
      for (int r = 0; r < 4; ++r)
        sG[(t * 16 + 4 * g + r) * 32 + 16 * j + le] = p4[r] * inv;
    }
  }
  __syncthreads();

  // ---- mix ----
  const int lrow = tid >> 4;
  const int lr = lr0 + lrow;       // chunk-local row
  const int grow = c0 + lr;        // global row
  const int cq = (tid & 15) * 8;   // col offset
  f32x4 am[8][2];
#pragma unroll
  for (int tt = 0; tt < 8; ++tt)
#pragma unroll
    for (int k = 0; k < 2; ++k) am[tt][k] = f32x4{0.f, 0.f, 0.f, 0.f};

  for (int ee = 0; ee < 16; ++ee) {
    const int tte = ee >> 1, eh = ee & 1;
    f16x8 ev = *(const f16x8*)(eo + ((size_t)ee * CH + lr) * 128 + cq);
    float evf[8];
#pragma unroll
    for (int z = 0; z < 8; ++z) evf[z] = (float)ev[z];
    float ssew = sw[(layer * 8 + tte) * 2 + eh];
#pragma unroll
    for (int tt = 0; tt < 8; ++tt) {
      float coef = sG[(tt * 16 + ee) * 32 + lrow] + (tt == tte ? ssew : 0.f);
#pragma unroll
      for (int z = 0; z < 8; ++z)
        am[tt][z >> 2][z & 3] = fmaf(coef, evf[z], am[tt][z >> 2][z & 3]);
    }
  }
#pragma unroll
  for (int tt = 0; tt < 8; ++tt) {
    size_t off = ((size_t)grow * 8 + tt) * 128 + cq;
    if (layer == 0) {
      f16x8 hv;
#pragma unroll
      for (int z = 0; z < 8; ++z) hv[z] = (f16)am[tt][z >> 2][z & 3];
      *(f16x8*)(x1out + off) = hv;
    } else {
      *(f32x4*)(fout + off) = am[tt][0];
      *(f32x4*)(fout + off + 4) = am[tt][1];
    }
  }
}

// ---------------------------------------------------------------------------
extern "C" void kernel_launch(void* const* d_in, const int* in_sizes, int n_in,
                              void* d_out, int out_size, void* d_ws, size_t ws_size,
                              hipStream_t stream) {
  const float* x0 = (const float*)d_in[0];
  const float* w1 = (const float*)d_in[1];
  const float* b1 = (const float*)d_in[2];
  const float* w2 = (const float*)d_in[3];
  const float* b2 = (const float*)d_in[4];
  const float* gw = (const float*)d_in[5];
  const float* gb = (const float*)d_in[6];
  const float* sw = (const float*)d_in[7];

  // ws bytes: w1T [0,1MB) | w2T [1MB,2MB) | gwT pair [2MB,+128KB)
  // | x1h fp16 [4MB,+64MB) | eo fp16 chunk [68MB,+32MB)  => 100MB
  f16* w1T = (f16*)d_ws;
  f16* w2T = (f16*)((char*)d_ws + 1048576);
  f16* gwT = (f16*)((char*)d_ws + 2097152);
  f16* x1h = (f16*)((char*)d_ws + 4194304);
  f16* eo = (f16*)((char*)d_ws + 71303168);
  float* out = (float*)d_out;

  kxform<<<528, 256, 0, stream>>>(w1, w2, gw, w1T, w2T, gwT);

  for (int c = 0; c < 4; ++c) {
    int c0 = c * CH;
    kexp<<<512, 256, 0, stream>>>(x0, x1h, w1T, w2T, b1, b2, eo, 0, c0);
    kmix<<<256, 512, 0, stream>>>(x0, x1h, gwT, gb, sw, eo, x1h, out, 0, c0);
    kexp<<<512, 256, 0, stream>>>(x0, x1h, w1T, w2T, b1, b2, eo, 1, c0);
    kmix<<<256, 512, 0, stream>>>(x0, x1h, gwT, gb, sw, eo, nullptr, out, 1, c0);
  }
}

// Round 17
// 275.658 us; speedup vs baseline: 1.1317x; 1.1317x over previous
//
#include <hip/hip_runtime.h>

// AdaTTSp on MI355X. B=32768, T=8, E=2, NE=16, D=H=128, L=2.
// Round 17 = r15/r16 split design with kexp staging switched from
// reg-staging (load->regs->ds_write) to __builtin_amdgcn_global_load_lds
// direct DMA (m151: 874 vs 646 TF precedent at the same tile shape):
//  - linear LDS dest, XOR swizzle moved into the per-lane GLOBAL source
//    address (m173 pattern); b-frag reads unchanged
//  - loads issued one tile ahead into the spare dbuf half; __syncthreads'
//    vmcnt drain = completion guarantee (m97 pattern)
//  - pre[]/stage_write gone -> lower VGPR, better weight residency
//  - kxcast restored (uniform fp16 x path both layers; kexp-l0 and kmix-l0
//    each save 64MB of f32 x reads)
//  - full-B launches (r16 chunking was neutral), e-major eo kept.

typedef float f32x4 __attribute__((ext_vector_type(4)));
typedef _Float16 f16;
typedef f16 f16x8 __attribute__((ext_vector_type(8)));
typedef f16 f16x4 __attribute__((ext_vector_type(4)));

#define MFMA(a, b, c) __builtin_amdgcn_mfma_f32_16x16x32_f16(a, b, c, 0, 0, 0)
#define LOSC (1.0f / 2048.0f)
#define AS1 __attribute__((address_space(1)))
#define AS3 __attribute__((address_space(3)))

__device__ __forceinline__ void split2h(float f, f16& h, f16& l) {
  h = (f16)f;
  l = (f16)((f - (float)h) * 2048.0f);
}

// ---------------------------------------------------------------------------
// x0 f32 -> fp16, natural [B][T][D] layout.
__global__ __launch_bounds__(256) void kxcast(const float* __restrict__ x0,
                                              f16* __restrict__ x0h) {
  size_t i = ((size_t)blockIdx.x * 256 + threadIdx.x) * 8;
  f32x4 f0 = *(const f32x4*)(x0 + i);
  f32x4 f1 = *(const f32x4*)(x0 + i + 4);
  f16x8 v;
#pragma unroll
  for (int z = 0; z < 4; ++z) {
    v[z] = (f16)f0[z];
    v[4 + z] = (f16)f1[z];
  }
  *(f16x8*)(x0h + i) = v;
}

// ---------------------------------------------------------------------------
// Weight transform. w1T/w2T: single-fp16 fragment arrays; gwT hi/lo pair.
__global__ __launch_bounds__(256) void kxform(
    const float* __restrict__ w1, const float* __restrict__ w2,
    const float* __restrict__ gw, f16* __restrict__ w1T,
    f16* __restrict__ w2T, f16* __restrict__ gwT) {
  int idx = blockIdx.x * 256 + threadIdx.x;
  if (idx < 131072) {
    const float* src = (idx < 65536) ? w1 : w2;
    f16* dst = (idx < 65536) ? w1T : w2T;
    int i = idx & 65535;
    int lane = i & 63;
    int it = (i >> 6) & 7;
    int ks = (i >> 9) & 3;
    int q = i >> 11;
    int g = lane >> 4, le = lane & 15;
    f16x8 vh;
#pragma unroll
    for (int j = 0; j < 8; ++j)
      vh[j] = (f16)src[((size_t)q * 128 + (32 * ks + 8 * g + j)) * 128 + 16 * it + le];
    *(f16x8*)(dst + (size_t)i * 8) = vh;
  } else {
    int i = idx - 131072;
    if (i >= 4096) return;
    int lane = i & 63;
    int ks = (i >> 6) & 3;
    int q = (i >> 8) & 15;
    int g = lane >> 4, le = lane & 15;
    f16x8 vh, vl;
#pragma unroll
    for (int j = 0; j < 8; ++j) {
      float f = gw[((size_t)q * 128 + (32 * ks + 8 * g + j)) * 16 + le];
      f16 h, l;
      split2h(f, h, l);
      vh[j] = h;
      vl[j] = l;
    }
    *(f16x8*)(gwT + (size_t)i * 8) = vh;
    *(f16x8*)(gwT + 32768 + (size_t)i * 8) = vl;
  }
}

// ---------------------------------------------------------------------------
// Expert kernel. grid = 32 rowblocks(1024) x 16 experts = 512 blocks;
// 256 thr (4 waves), 2 blocks/CU. 16 tiles x 64 rows.
// Staging: global_load_lds, 16B/lane, linear LDS; swizzle folded into the
// per-lane global source: LDS[row][gc] = x[row][gc ^ (row&7)].
// b-frag read (unchanged): [brow][8*((G)^(brow&7))] for wanted granule G.
__global__ __launch_bounds__(256, 2) void kexp(
    const f16* __restrict__ xs, const f16* __restrict__ w1T,
    const f16* __restrict__ w2T, const float* __restrict__ b1,
    const float* __restrict__ b2, f16* __restrict__ eo, int layer) {
  __shared__ f16 sX[2][8192];  // 64 x 128, dbuf (32KB)
  __shared__ f16 sH[8192];     // 16KB
  __shared__ f16 sEO[8192];    // 16KB
  const int tid = threadIdx.x;
  const int lane = tid & 63;
  const int it2 = tid >> 6;  // wave id = oc 32-tile
  const int g = lane >> 4, le = lane & 15;
  const int e = blockIdx.x & 15;
  const int r0 = (blockIdx.x >> 4) * 1024;
  const int te = e >> 1;
  const int lx = layer * 16 + e;

  // ---- resident single-fp16 weight fragments (it = 2*it2 + i2): 64 VGPR ----
  f16x8 w1r[2][4], w2r[2][4];
#pragma unroll
  for (int i2 = 0; i2 < 2; ++i2)
#pragma unroll
    for (int ks = 0; ks < 4; ++ks) {
      size_t fb = ((size_t)((lx * 4 + ks) * 8 + 2 * it2 + i2) * 64 + lane) * 8;
      w1r[i2][ks] = *(const f16x8*)(w1T + fb);
      w2r[i2][ks] = *(const f16x8*)(w2T + fb);
    }
  f32x4 b1v[2], b2v[2];
#pragma unroll
  for (int i2 = 0; i2 < 2; ++i2) {
    b1v[i2] = *(const f32x4*)(b1 + lx * 128 + 32 * it2 + 16 * i2 + 4 * g);
    b2v[i2] = *(const f32x4*)(b2 + lx * 128 + 32 * it2 + 16 * i2 + 4 * g);
  }

  // ---- direct global->LDS staging: wave it2 covers rows 16*it2..16*it2+15,
  //      4 instructions x 1KB (4 rows each). lane -> row 4i+(lane>>4),
  //      granule gc = lane&15; source granule = gc ^ (row&7).
  auto stage_gl = [&](int buf, int tile) {
#pragma unroll
    for (int i = 0; i < 4; ++i) {
      int row = 16 * it2 + 4 * i + (lane >> 4);
      int gc = lane & 15;
      const f16* src = xs + ((size_t)(r0 + tile * 64 + row) * 8 + te) * 128 +
                       (gc ^ (row & 7)) * 8;
      f16* dst = &sX[buf][(16 * it2 + 4 * i) * 128];
      __builtin_amdgcn_global_load_lds((const AS1 void*)src, (AS3 void*)dst,
                                       16, 0, 0);
    }
  };
  // ---- contiguous e-major eo flush ----
  auto eo_flush = [&](int tile) {
#pragma unroll
    for (int i = 0; i < 4; ++i) {
      int slot = i * 256 + tid;
      int row = slot >> 4, c = slot & 15;
      f16x8 v = *(const f16x8*)(&sEO[row * 128 + 8 * (c ^ (row & 7))]);
      *(f16x8*)(eo + ((size_t)e * 32768 + (r0 + tile * 64 + row)) * 128 + 8 * c) = v;
    }
  };

  stage_gl(0, 0);
  __syncthreads();  // drains the DMA (vmcnt), sX[0] ready

  for (int tile = 0; tile < 16; ++tile) {
    const int b = tile & 1;
    if (tile < 15) stage_gl(b ^ 1, tile + 1);  // in flight across GEMM1+GEMM2
    if (tile > 0) eo_flush(tile - 1);
    // ---- GEMM1: h = relu(w1^T x^T + b1) -> sH ----
    {
      f32x4 a[2][4];
#pragma unroll
      for (int i2 = 0; i2 < 2; ++i2)
#pragma unroll
        for (int j = 0; j < 4; ++j) a[i2][j] = f32x4{0.f, 0.f, 0.f, 0.f};
#pragma unroll
      for (int ks = 0; ks < 4; ++ks)
#pragma unroll
        for (int j = 0; j < 4; ++j) {
          int brow = 16 * j + le;
          f16x8 bf = *(const f16x8*)(&sX[b][brow * 128 + 8 * ((4 * ks + g) ^ (brow & 7))]);
#pragma unroll
          for (int i2 = 0; i2 < 2; ++i2)
            a[i2][j] = MFMA(w1r[i2][ks], bf, a[i2][j]);
        }
#pragma unroll
      for (int i2 = 0; i2 < 2; ++i2)
#pragma unroll
        for (int j = 0; j < 4; ++j) {
          int brow = 16 * j + le;
          f16x4 hv;
#pragma unroll
          for (int r = 0; r < 4; ++r)
            hv[r] = (f16)fmaxf(a[i2][j][r] + b1v[i2][r], 0.f);
          *(f16x4*)(&sH[brow * 128 + 8 * ((4 * it2 + 2 * i2 + (g >> 1)) ^ (brow & 7)) +
                        4 * (g & 1)]) = hv;
        }
    }
    __syncthreads();
    // ---- GEMM2: eo = relu(w2^T h^T + b2) -> sEO ----
    {
      f32x4 a[2][4];
#pragma unroll
      for (int i2 = 0; i2 < 2; ++i2)
#pragma unroll
        for (int j = 0; j < 4; ++j) a[i2][j] = f32x4{0.f, 0.f, 0.f, 0.f};
#pragma unroll
      for (int ks = 0; ks < 4; ++ks)
#pragma unroll
        for (int j = 0; j < 4; ++j) {
          int brow = 16 * j + le;
          f16x8 bf = *(const f16x8*)(&sH[brow * 128 + 8 * ((4 * ks + g) ^ (brow & 7))]);
#pragma unroll
          for (int i2 = 0; i2 < 2; ++i2)
            a[i2][j] = MFMA(w2r[i2][ks], bf, a[i2][j]);
        }
#pragma unroll
      for (int i2 = 0; i2 < 2; ++i2)
#pragma unroll
        for (int j = 0; j < 4; ++j) {
          int brow = 16 * j + le;
          f16x4 ev;
#pragma unroll
          for (int r = 0; r < 4; ++r)
            ev[r] = (f16)fmaxf(a[i2][j][r] + b2v[i2][r], 0.f);
          *(f16x4*)(&sEO[brow * 128 + 8 * ((4 * it2 + 2 * i2 + (g >> 1)) ^ (brow & 7)) +
                         4 * (g & 1)]) = ev;
        }
    }
    __syncthreads();  // drains next-tile DMA too (issued ~2 GEMMs ago)
  }
  eo_flush(15);
}

// ---------------------------------------------------------------------------
// Gate + mix kernel. grid = 1024 blocks (32 rows), 512 thr (8 waves).
// x fp16 both layers; eo e-major.
__global__ __launch_bounds__(512, 4) void kmix(
    const f16* __restrict__ xs, const f16* __restrict__ gwT,
    const float* __restrict__ gb, const float* __restrict__ sw,
    const f16* __restrict__ eo, f16* __restrict__ x1out,
    float* __restrict__ fout, int layer) {
  __shared__ float sG[8 * 16 * 32];  // [t][e][row32] 16KB
  const int tid = threadIdx.x;
  const int lane = tid & 63;
  const int t = tid >> 6;
  const int g = lane >> 4, le = lane & 15;
  const int r0 = blockIdx.x * 32;
  const int lt = layer * 8 + t;

  {  // ---- gates ----
    f32x4 l1[2], l2[2];
#pragma unroll
    for (int j = 0; j < 2; ++j) {
      l1[j] = f32x4{0.f, 0.f, 0.f, 0.f};
      l2[j] = f32x4{0.f, 0.f, 0.f, 0.f};
    }
#pragma unroll
    for (int ks = 0; ks < 4; ++ks) {
      size_t fb = ((size_t)(lt * 4 + ks) * 64 + lane) * 8;
      f16x8 ah = *(const f16x8*)(gwT + fb);
      f16x8 al = *(const f16x8*)(gwT + 32768 + fb);
#pragma unroll
      for (int j = 0; j < 2; ++j) {
        f16x8 bf = *(const f16x8*)(xs + ((size_t)(r0 + 16 * j + le) * 8 + t) * 128 +
                                   32 * ks + 8 * g);
        l1[j] = MFMA(ah, bf, l1[j]);
        l2[j] = MFMA(al, bf, l2[j]);
      }
    }
#pragma unroll
    for (int j = 0; j < 2; ++j) {
      float zb[4];
#pragma unroll
      for (int r = 0; r < 4; ++r)
        zb[r] = l1[j][r] + l2[j][r] * LOSC + gb[lt * 16 + 4 * g + r];
      float m4 = fmaxf(fmaxf(zb[0], zb[1]), fmaxf(zb[2], zb[3]));
      m4 = fmaxf(m4, __shfl_xor(m4, 16, 64));
      m4 = fmaxf(m4, __shfl_xor(m4, 32, 64));
      float p4[4], s4 = 0.f;
#pragma unroll
      for (int r = 0; r < 4; ++r) {
        p4[r] = __expf(zb[r] - m4);
        s4 += p4[r];
      }
      s4 += __shfl_xor(s4, 16, 64);
      s4 += __shfl_xor(s4, 32, 64);
      float inv = 1.f / s4;
#pragma unroll
      for (int r = 0; r < 4; ++r)
        sG[(t * 16 + 4 * g + r) * 32 + 16 * j + le] = p4[r] * inv;
    }
  }
  __syncthreads();

  // ---- mix ----
  const int lrow = tid >> 4;
  const int grow = r0 + lrow;
  const int cq = (tid & 15) * 8;
  f32x4 am[8][2];
#pragma unroll
  for (int tt = 0; tt < 8; ++tt)
#pragma unroll
    for (int k = 0; k < 2; ++k) am[tt][k] = f32x4{0.f, 0.f, 0.f, 0.f};

  for (int ee = 0; ee < 16; ++ee) {
    const int tte = ee >> 1, eh = ee & 1;
    f16x8 ev = *(const f16x8*)(eo + ((size_t)ee * 32768 + grow) * 128 + cq);
    float evf[8];
#pragma unroll
    for (int z = 0; z < 8; ++z) evf[z] = (float)ev[z];
    float ssew = sw[(layer * 8 + tte) * 2 + eh];
#pragma unroll
    for (int tt = 0; tt < 8; ++tt) {
      float coef = sG[(tt * 16 + ee) * 32 + lrow] + (tt == tte ? ssew : 0.f);
#pragma unroll
      for (int z = 0; z < 8; ++z)
        am[tt][z >> 2][z & 3] = fmaf(coef, evf[z], am[tt][z >> 2][z & 3]);
    }
  }
#pragma unroll
  for (int tt = 0; tt < 8; ++tt) {
    size_t off = ((size_t)grow * 8 + tt) * 128 + cq;
    if (layer == 0) {
      f16x8 hv;
#pragma unroll
      for (int z = 0; z < 8; ++z) hv[z] = (f16)am[tt][z >> 2][z & 3];
      *(f16x8*)(x1out + off) = hv;
    } else {
      *(f32x4*)(fout + off) = am[tt][0];
      *(f32x4*)(fout + off + 4) = am[tt][1];
    }
  }
}

// ---------------------------------------------------------------------------
extern "C" void kernel_launch(void* const* d_in, const int* in_sizes, int n_in,
                              void* d_out, int out_size, void* d_ws, size_t ws_size,
                              hipStream_t stream) {
  const float* x0 = (const float*)d_in[0];
  const float* w1 = (const float*)d_in[1];
  const float* b1 = (const float*)d_in[2];
  const float* w2 = (const float*)d_in[3];
  const float* b2 = (const float*)d_in[4];
  const float* gw = (const float*)d_in[5];
  const float* gb = (const float*)d_in[6];
  const float* sw = (const float*)d_in[7];

  // ws bytes: w1T [0,1MB) | w2T [1MB,2MB) | gwT pair [2MB,+128KB)
  // | x0h fp16 [4MB,+64MB) | x1h fp16 [68MB,+64MB) | eo fp16 [132MB,+128MB)
  f16* w1T = (f16*)d_ws;
  f16* w2T = (f16*)((char*)d_ws + 1048576);
  f16* gwT = (f16*)((char*)d_ws + 2097152);
  f16* x0h = (f16*)((char*)d_ws + 4194304);
  f16* x1h = (f16*)((char*)d_ws + 71303168);
  f16* eo = (f16*)((char*)d_ws + 138412032);
  float* out = (float*)d_out;

  kxform<<<528, 256, 0, stream>>>(w1, w2, gw, w1T, w2T, gwT);
  kxcast<<<16384, 256, 0, stream>>>(x0, x0h);

  kexp<<<512, 256, 0, stream>>>(x0h, w1T, w2T, b1, b2, eo, 0);
  kmix<<<1024, 512, 0, stream>>>(x0h, gwT, gb, sw, eo, x1h, nullptr, 0);
  kexp<<<512, 256, 0, stream>>>(x1h, w1T, w2T, b1, b2, eo, 1);
  kmix<<<1024, 512, 0, stream>>>(x1h, gwT, gb, sw, eo, nullptr, out, 1);
}

// Round 18
// 269.672 us; speedup vs baseline: 1.1568x; 1.0222x over previous
//
#include <hip/hip_runtime.h>

// AdaTTSp on MI355X. B=32768, T=8, E=2, NE=16, D=H=128, L=2.
// Round 18 = r17 with (a) kexp wave remap: wave = 32 rows x 64 oc
// (4 it-tiles, weights 128 VGPR) so each b-frag ds_read_b128 feeds 4 MFMAs
// (was 2) -> block LDS reads/tile halved 128->64 (~10us/layer of ds issue);
// (b) kxform+kxcast merged into one kprep launch.
// Staging (global_load_lds DMA, src-swizzled), e-major eo, kmix: r17 verbatim.

typedef float f32x4 __attribute__((ext_vector_type(4)));
typedef _Float16 f16;
typedef f16 f16x8 __attribute__((ext_vector_type(8)));
typedef f16 f16x4 __attribute__((ext_vector_type(4)));

#define MFMA(a, b, c) __builtin_amdgcn_mfma_f32_16x16x32_f16(a, b, c, 0, 0, 0)
#define LOSC (1.0f / 2048.0f)
#define AS1 __attribute__((address_space(1)))
#define AS3 __attribute__((address_space(3)))

__device__ __forceinline__ void split2h(float f, f16& h, f16& l) {
  h = (f16)f;
  l = (f16)((f - (float)h) * 2048.0f);
}

// ---------------------------------------------------------------------------
// Merged prep: blocks [0,16384) cast x0 f32->fp16; blocks [16384,16912)
// transform weights (w1T/w2T single-fp16 fragments; gwT hi/lo pair).
__global__ __launch_bounds__(256) void kprep(
    const float* __restrict__ x0, const float* __restrict__ w1,
    const float* __restrict__ w2, const float* __restrict__ gw,
    f16* __restrict__ x0h, f16* __restrict__ w1T, f16* __restrict__ w2T,
    f16* __restrict__ gwT) {
  int bid = blockIdx.x;
  int tid = threadIdx.x;
  if (bid < 16384) {
    size_t i = ((size_t)bid * 256 + tid) * 8;
    f32x4 f0 = *(const f32x4*)(x0 + i);
    f32x4 f1 = *(const f32x4*)(x0 + i + 4);
    f16x8 v;
#pragma unroll
    for (int z = 0; z < 4; ++z) {
      v[z] = (f16)f0[z];
      v[4 + z] = (f16)f1[z];
    }
    *(f16x8*)(x0h + i) = v;
    return;
  }
  int idx = (bid - 16384) * 256 + tid;
  if (idx < 131072) {
    const float* src = (idx < 65536) ? w1 : w2;
    f16* dst = (idx < 65536) ? w1T : w2T;
    int i = idx & 65535;
    int lane = i & 63;
    int it = (i >> 6) & 7;
    int ks = (i >> 9) & 3;
    int q = i >> 11;
    int g = lane >> 4, le = lane & 15;
    f16x8 vh;
#pragma unroll
    for (int j = 0; j < 8; ++j)
      vh[j] = (f16)src[((size_t)q * 128 + (32 * ks + 8 * g + j)) * 128 + 16 * it + le];
    *(f16x8*)(dst + (size_t)i * 8) = vh;
  } else {
    int i = idx - 131072;  // 0..4095
    int lane = i & 63;
    int ks = (i >> 6) & 3;
    int q = (i >> 8) & 15;
    int g = lane >> 4, le = lane & 15;
    f16x8 vh, vl;
#pragma unroll
    for (int j = 0; j < 8; ++j) {
      float f = gw[((size_t)q * 128 + (32 * ks + 8 * g + j)) * 16 + le];
      f16 h, l;
      split2h(f, h, l);
      vh[j] = h;
      vl[j] = l;
    }
    *(f16x8*)(gwT + (size_t)i * 8) = vh;
    *(f16x8*)(gwT + 32768 + (size_t)i * 8) = vl;
  }
}

// ---------------------------------------------------------------------------
// Expert kernel. grid = 32 rowblocks(1024) x 16 experts = 512 blocks;
// 256 thr (4 waves), 2 blocks/CU. 16 tiles x 64 rows.
// Wave = (jh = wave&1: 32-row half, oh = wave>>1: 64-oc half).
// Weights in regs: w{1,2}r[it 0..3][ks] = 128 VGPR; b-frag read feeds 4 MFMA.
// Staging: global_load_lds, swizzle in the global source (r17, verified).
__global__ __launch_bounds__(256, 2) void kexp(
    const f16* __restrict__ xs, const f16* __restrict__ w1T,
    const f16* __restrict__ w2T, const float* __restrict__ b1,
    const float* __restrict__ b2, f16* __restrict__ eo, int layer) {
  __shared__ f16 sX[2][8192];  // 64 x 128, dbuf (32KB)
  __shared__ f16 sH[8192];     // 16KB
  __shared__ f16 sEO[8192];    // 16KB
  const int tid = threadIdx.x;
  const int lane = tid & 63;
  const int wave = tid >> 6;
  const int jh = wave & 1, oh = wave >> 1;
  const int g = lane >> 4, le = lane & 15;
  const int e = blockIdx.x & 15;
  const int r0 = (blockIdx.x >> 4) * 1024;
  const int te = e >> 1;
  const int lx = layer * 16 + e;

  // ---- resident weight fragments: it_global = 4*oh + it ----
  f16x8 w1r[4][4], w2r[4][4];
#pragma unroll
  for (int it = 0; it < 4; ++it)
#pragma unroll
    for (int ks = 0; ks < 4; ++ks) {
      size_t fb = ((size_t)((lx * 4 + ks) * 8 + 4 * oh + it) * 64 + lane) * 8;
      w1r[it][ks] = *(const f16x8*)(w1T + fb);
      w2r[it][ks] = *(const f16x8*)(w2T + fb);
    }
  f32x4 b1v[4], b2v[4];
#pragma unroll
  for (int it = 0; it < 4; ++it) {
    b1v[it] = *(const f32x4*)(b1 + lx * 128 + 64 * oh + 16 * it + 4 * g);
    b2v[it] = *(const f32x4*)(b2 + lx * 128 + 64 * oh + 16 * it + 4 * g);
  }

  // ---- direct global->LDS staging (r17): wave covers rows 16w..16w+15 ----
  auto stage_gl = [&](int buf, int tile) {
#pragma unroll
    for (int i = 0; i < 4; ++i) {
      int row = 16 * wave + 4 * i + (lane >> 4);
      int gc = lane & 15;
      const f16* src = xs + ((size_t)(r0 + tile * 64 + row) * 8 + te) * 128 +
                       (gc ^ (row & 7)) * 8;
      f16* dst = &sX[buf][(16 * wave + 4 * i) * 128];
      __builtin_amdgcn_global_load_lds((const AS1 void*)src, (AS3 void*)dst,
                                       16, 0, 0);
    }
  };
  // ---- contiguous e-major eo flush ----
  auto eo_flush = [&](int tile) {
#pragma unroll
    for (int i = 0; i < 4; ++i) {
      int slot = i * 256 + tid;
      int row = slot >> 4, c = slot & 15;
      f16x8 v = *(const f16x8*)(&sEO[row * 128 + 8 * (c ^ (row & 7))]);
      *(f16x8*)(eo + ((size_t)e * 32768 + (r0 + tile * 64 + row)) * 128 + 8 * c) = v;
    }
  };

  stage_gl(0, 0);
  __syncthreads();

  for (int tile = 0; tile < 16; ++tile) {
    const int b = tile & 1;
    if (tile < 15) stage_gl(b ^ 1, tile + 1);
    if (tile > 0) eo_flush(tile - 1);
    // ---- GEMM1: h = relu(w1^T x^T + b1) -> sH ----
    {
      f32x4 a[4][2];
#pragma unroll
      for (int it = 0; it < 4; ++it)
#pragma unroll
        for (int j2 = 0; j2 < 2; ++j2) a[it][j2] = f32x4{0.f, 0.f, 0.f, 0.f};
#pragma unroll
      for (int ks = 0; ks < 4; ++ks)
#pragma unroll
        for (int j2 = 0; j2 < 2; ++j2) {
          int brow = 32 * jh + 16 * j2 + le;
          f16x8 bf = *(const f16x8*)(&sX[b][brow * 128 + 8 * ((4 * ks + g) ^ (brow & 7))]);
#pragma unroll
          for (int it = 0; it < 4; ++it)
            a[it][j2] = MFMA(w1r[it][ks], bf, a[it][j2]);
        }
#pragma unroll
      for (int it = 0; it < 4; ++it)
#pragma unroll
        for (int j2 = 0; j2 < 2; ++j2) {
          int brow = 32 * jh + 16 * j2 + le;
          f16x4 hv;
#pragma unroll
          for (int r = 0; r < 4; ++r)
            hv[r] = (f16)fmaxf(a[it][j2][r] + b1v[it][r], 0.f);
          int gran = 8 * oh + 2 * it + (g >> 1);
          *(f16x4*)(&sH[brow * 128 + 8 * (gran ^ (brow & 7)) + 4 * (g & 1)]) = hv;
        }
    }
    __syncthreads();
    // ---- GEMM2: eo = relu(w2^T h^T + b2) -> sEO ----
    {
      f32x4 a[4][2];
#pragma unroll
      for (int it = 0; it < 4; ++it)
#pragma unroll
        for (int j2 = 0; j2 < 2; ++j2) a[it][j2] = f32x4{0.f, 0.f, 0.f, 0.f};
#pragma unroll
      for (int ks = 0; ks < 4; ++ks)
#pragma unroll
        for (int j2 = 0; j2 < 2; ++j2) {
          int brow = 32 * jh + 16 * j2 + le;
          f16x8 bf = *(const f16x8*)(&sH[brow * 128 + 8 * ((4 * ks + g) ^ (brow & 7))]);
#pragma unroll
          for (int it = 0; it < 4; ++it)
            a[it][j2] = MFMA(w2r[it][ks], bf, a[it][j2]);
        }
#pragma unroll
      for (int it = 0; it < 4; ++it)
#pragma unroll
        for (int j2 = 0; j2 < 2; ++j2) {
          int brow = 32 * jh + 16 * j2 + le;
          f16x4 ev;
#pragma unroll
          for (int r = 0; r < 4; ++r)
            ev[r] = (f16)fmaxf(a[it][j2][r] + b2v[it][r], 0.f);
          int gran = 8 * oh + 2 * it + (g >> 1);
          *(f16x4*)(&sEO[brow * 128 + 8 * (gran ^ (brow & 7)) + 4 * (g & 1)]) = ev;
        }
    }
    // ---- pin weight residency across the loop ----
#pragma unroll
    for (int it = 0; it < 4; ++it)
#pragma unroll
      for (int ks = 0; ks < 4; ++ks) {
        asm volatile("" : "+v"(w1r[it][ks]));
        asm volatile("" : "+v"(w2r[it][ks]));
      }
    __syncthreads();
  }
  eo_flush(15);
}

// ---------------------------------------------------------------------------
// Gate + mix kernel (r17 verbatim). grid = 1024 blocks (32 rows), 512 thr.
__global__ __launch_bounds__(512, 4) void kmix(
    const f16* __restrict__ xs, const f16* __restrict__ gwT,
    const float* __restrict__ gb, const float* __restrict__ sw,
    const f16* __restrict__ eo, f16* __restrict__ x1out,
    float* __restrict__ fout, int layer) {
  __shared__ float sG[8 * 16 * 32];  // [t][e][row32] 16KB
  const int tid = threadIdx.x;
  const int lane = tid & 63;
  const int t = tid >> 6;
  const int g = lane >> 4, le = lane & 15;
  const int r0 = blockIdx.x * 32;
  const int lt = layer * 8 + t;

  {  // ---- gates ----
    f32x4 l1[2], l2[2];
#pragma unroll
    for (int j = 0; j < 2; ++j) {
      l1[j] = f32x4{0.f, 0.f, 0.f, 0.f};
      l2[j] = f32x4{0.f, 0.f, 0.f, 0.f};
    }
#pragma unroll
    for (int ks = 0; ks < 4; ++ks) {
      size_t fb = ((size_t)(lt * 4 + ks) * 64 + lane) * 8;
      f16x8 ah = *(const f16x8*)(gwT + fb);
      f16x8 al = *(const f16x8*)(gwT + 32768 + fb);
#pragma unroll
      for (int j = 0; j < 2; ++j) {
        f16x8 bf = *(const f16x8*)(xs + ((size_t)(r0 + 16 * j + le) * 8 + t) * 128 +
                                   32 * ks + 8 * g);
        l1[j] = MFMA(ah, bf, l1[j]);
        l2[j] = MFMA(al, bf, l2[j]);
      }
    }
#pragma unroll
    for (int j = 0; j < 2; ++j) {
      float zb[4];
#pragma unroll
      for (int r = 0; r < 4; ++r)
        zb[r] = l1[j][r] + l2[j][r] * LOSC + gb[lt * 16 + 4 * g + r];
      float m4 = fmaxf(fmaxf(zb[0], zb[1]), fmaxf(zb[2], zb[3]));
      m4 = fmaxf(m4, __shfl_xor(m4, 16, 64));
      m4 = fmaxf(m4, __shfl_xor(m4, 32, 64));
      float p4[4], s4 = 0.f;
#pragma unroll
      for (int r = 0; r < 4; ++r) {
        p4[r] = __expf(zb[r] - m4);
        s4 += p4[r];
      }
      s4 += __shfl_xor(s4, 16, 64);
      s4 += __shfl_xor(s4, 32, 64);
      float inv = 1.f / s4;
#pragma unroll
      for (int r = 0; r < 4; ++r)
        sG[(t * 16 + 4 * g + r) * 32 + 16 * j + le] = p4[r] * inv;
    }
  }
  __syncthreads();

  // ---- mix ----
  const int lrow = tid >> 4;
  const int grow = r0 + lrow;
  const int cq = (tid & 15) * 8;
  f32x4 am[8][2];
#pragma unroll
  for (int tt = 0; tt < 8; ++tt)
#pragma unroll
    for (int k = 0; k < 2; ++k) am[tt][k] = f32x4{0.f, 0.f, 0.f, 0.f};

  for (int ee = 0; ee < 16; ++ee) {
    const int tte = ee >> 1, eh = ee & 1;
    f16x8 ev = *(const f16x8*)(eo + ((size_t)ee * 32768 + grow) * 128 + cq);
    float evf[8];
#pragma unroll
    for (int z = 0; z < 8; ++z) evf[z] = (float)ev[z];
    float ssew = sw[(layer * 8 + tte) * 2 + eh];
#pragma unroll
    for (int tt = 0; tt < 8; ++tt) {
      float coef = sG[(tt * 16 + ee) * 32 + lrow] + (tt == tte ? ssew : 0.f);
#pragma unroll
      for (int z = 0; z < 8; ++z)
        am[tt][z >> 2][z & 3] = fmaf(coef, evf[z], am[tt][z >> 2][z & 3]);
    }
  }
#pragma unroll
  for (int tt = 0; tt < 8; ++tt) {
    size_t off = ((size_t)grow * 8 + tt) * 128 + cq;
    if (layer == 0) {
      f16x8 hv;
#pragma unroll
      for (int z = 0; z < 8; ++z) hv[z] = (f16)am[tt][z >> 2][z & 3];
      *(f16x8*)(x1out + off) = hv;
    } else {
      *(f32x4*)(fout + off) = am[tt][0];
      *(f32x4*)(fout + off + 4) = am[tt][1];
    }
  }
}

// ---------------------------------------------------------------------------
extern "C" void kernel_launch(void* const* d_in, const int* in_sizes, int n_in,
                              void* d_out, int out_size, void* d_ws, size_t ws_size,
                              hipStream_t stream) {
  const float* x0 = (const float*)d_in[0];
  const float* w1 = (const float*)d_in[1];
  const float* b1 = (const float*)d_in[2];
  const float* w2 = (const float*)d_in[3];
  const float* b2 = (const float*)d_in[4];
  const float* gw = (const float*)d_in[5];
  const float* gb = (const float*)d_in[6];
  const float* sw = (const float*)d_in[7];

  // ws bytes: w1T [0,1MB) | w2T [1MB,2MB) | gwT pair [2MB,+128KB)
  // | x0h fp16 [4MB,+64MB) | x1h fp16 [68MB,+64MB) | eo fp16 [132MB,+128MB)
  f16* w1T = (f16*)d_ws;
  f16* w2T = (f16*)((char*)d_ws + 1048576);
  f16* gwT = (f16*)((char*)d_ws + 2097152);
  f16* x0h = (f16*)((char*)d_ws + 4194304);
  f16* x1h = (f16*)((char*)d_ws + 71303168);
  f16* eo = (f16*)((char*)d_ws + 138412032);
  float* out = (float*)d_out;

  kprep<<<16912, 256, 0, stream>>>(x0, w1, w2, gw, x0h, w1T, w2T, gwT);

  kexp<<<512, 256, 0, stream>>>(x0h, w1T, w2T, b1, b2, eo, 0);
  kmix<<<1024, 512, 0, stream>>>(x0h, gwT, gb, sw, eo, x1h, nullptr, 0);
  kexp<<<512, 256, 0, stream>>>(x1h, w1T, w2T, b1, b2, eo, 1);
  kmix<<<1024, 512, 0, stream>>>(x1h, gwT, gb, sw, eo, nullptr, out, 1);
}